// Round 5
// baseline (1653.508 us; speedup 1.0000x reference)
//
#include <hip/hip_runtime.h>
#include <hip/hip_bf16.h>
#include <math.h>

#define Bdim 32
#define Ndim 512
#define Hdim 768
#define Rdim 5
#define Ldim 2
#define FFdim 1536
#define LN_EPS 1e-5f

typedef __attribute__((ext_vector_type(8))) __bf16 bf16x8;
typedef __attribute__((ext_vector_type(8))) unsigned short ushort8;
typedef __attribute__((ext_vector_type(4))) float f32x4;

__device__ __forceinline__ unsigned short f2bf(float f) {
  union { float f; unsigned int u; } x;
  x.f = f;
  unsigned int u = x.u;
  return (unsigned short)((u + 0x7FFFu + ((u >> 16) & 1u)) >> 16);  // RTNE
}

__device__ __forceinline__ void gload_lds16(const unsigned short* g, unsigned short* l) {
  __builtin_amdgcn_global_load_lds(
      (const __attribute__((address_space(1))) void*)g,
      (__attribute__((address_space(3))) void*)l, 16, 0, 0);
}

// ---------------------------------------------------------------------------
// MFMA bf16 GEMM: C[M,N] = A[M,K] @ B[K,N]; A bf16 row-major, B TRANSPOSED
// bf16 (Bt[n][k], k-contiguous).
// BM=256, BN=128, BK=64. 8 waves (4M x 2N), wave tile 64x64 (acc[4][4]).
// Deep pipeline, 2 phases per K-tile:
//   ph a: vmcnt(2); barrier; ds_read B-frags(8)+A-q0(4); stage A[t+1](4 calls);
//         lgkmcnt(0); sched_barrier; setprio(1); 16 MFMA; setprio(0); barrier
//   ph b: ds_read A-q1(4); stage B[t+2](2 calls); lgkmcnt(0); sched_barrier;
//         setprio(1); 16 MFMA; setprio(0)
// vmcnt never drains to 0 except the final K-tile. LDS 96 KiB (2x A 32K, 2x B 16K).
// T2 XOR-swizzle: staged via pre-swizzled GLOBAL source col (cs=(l&7)^(l>>3)),
// read back with slot = cs ^ (row&7) -> uniform bank spread.
// XCD-chunked bijective block remap (T1/m204).
// NSEG K-segments of segK each (NSEG=1 for plain GEMM).
// EPI 0: C = A@B                           (agg)              -> bf16
// EPI 1: C = sum_seg wv[b,seg]*relu(A_seg@B_seg + bias_seg)   -> bf16
// EPI 2: C = A@B + bias + resid            (out proj / ffn2)  -> f32
// EPI 3: C = relu(A@B + bias)              (ffn1)             -> bf16
// ---------------------------------------------------------------------------
template <int EPI, bool OUT_BF16, int NSEG>
__global__ __launch_bounds__(512, 2) void mfma_gemm(
    const unsigned short* __restrict__ A, long sA, long sA2, int lda,
    const unsigned short* __restrict__ Bt, long sB, int ldb,
    void* __restrict__ Cp, long sC, int ldc,
    int segK, long segA, long segB,
    const float* __restrict__ bias,
    const float* __restrict__ resid,
    const float* __restrict__ wv) {
  __shared__ __align__(16) unsigned short As[2 * 256 * 64];  // 64 KiB
  __shared__ __align__(16) unsigned short Bs[2 * 128 * 64];  // 32 KiB

  // ---- XCD-chunked bijective block remap (T1, m204) ----
  const int gx = gridDim.x, gy = gridDim.y;
  int lin = blockIdx.x + gx * (blockIdx.y + gy * blockIdx.z);
  {
    const int total = gx * gy * gridDim.z;
    const int q = total >> 3, r8 = total & 7;
    const int xcd = lin & 7, slot = lin >> 3;
    lin = (xcd < r8) ? (xcd * (q + 1) + slot)
                     : (r8 * (q + 1) + (xcd - r8) * q + slot);
  }
  const int bx = lin % gx;
  const int tv = lin / gx;
  const int by = tv % gy;
  const int zb = tv / gy;

  const int zlo = zb & 31;   // b
  const int zhi = zb >> 5;   // r (agg batching); 0 elsewhere
  const int row0 = by * 256;
  const int col0 = bx * 128;
  const int tid = threadIdx.x;
  const int wid = tid >> 6;        // 0..7
  const int lane = tid & 63;
  const int wr = wid >> 1;         // 0..3: 64-row quadrant
  const int wc = wid & 1;          // 0..1: 64-col half
  const int lr = lane & 15;
  const int lks = lane >> 4;       // 0..3

  // staging lane geometry (pre-swizzled global source)
  const int rl = lane >> 3;                  // row within 8-row chunk
  const int cl = ((lane & 7) ^ rl) * 8;      // swizzled source col (elems)

  const unsigned short* Abase = A + (long)zlo * sA + (long)zhi * sA2;
  const unsigned short* Bbase = Bt + (long)zlo * sB;

  // EPI1 per-seg constants (issued first -> oldest in vm queue)
  float pw[NSEG], pb[NSEG][4];
  if (EPI == 1) {
#pragma unroll
    for (int s = 0; s < NSEG; s++) {
      pw[s] = wv[(row0 >> 9) * Rdim + s];
#pragma unroll
      for (int fc = 0; fc < 4; fc++)
        pb[s][fc] = bias[s * Hdim + col0 + wc * 64 + fc * 16 + lr];
    }
  }

  f32x4 acc[4][4], acc2[4][4];
#pragma unroll
  for (int i = 0; i < 4; i++)
#pragma unroll
    for (int j = 0; j < 4; j++) {
      acc[i][j] = (f32x4){0.f, 0.f, 0.f, 0.f};
      if (EPI == 1) acc2[i][j] = (f32x4){0.f, 0.f, 0.f, 0.f};
    }

  const int spt = segK >> 6;        // K-tiles per segment
  const int T = NSEG * spt;
  int aseg = 0, ak = 0, bseg = 0, bk = 0;   // staging cursors

  auto stageA = [&](int parity) {   // full A K-tile: 4 calls/thread (32 KiB)
    const unsigned short* s0 = Abase + (long)aseg * segA + ak;
#pragma unroll
    for (int q = 0; q < 4; q++) {
      const int ch = wid * 4 + q;   // 8-row chunk
      gload_lds16(s0 + (long)(row0 + ch * 8 + rl) * lda + cl,
                  As + parity * 16384 + ch * 512);
    }
    ak += 64;
    if (ak == segK) { ak = 0; aseg++; }
  };
  auto stageB = [&](int parity) {   // full B K-tile: 2 calls/thread (16 KiB)
    const unsigned short* s0 = Bbase + (long)bseg * segB + bk;
#pragma unroll
    for (int q = 0; q < 2; q++) {
      const int ch = wid * 2 + q;
      gload_lds16(s0 + (long)(col0 + ch * 8 + rl) * ldb + cl,
                  Bs + parity * 8192 + ch * 512);
    }
    bk += 64;
    if (bk == segK) { bk = 0; bseg++; }
  };

  // prologue: A[0]->As[0], B[0]->Bs[0], B[1]->Bs[1]
  stageA(0);
  stageB(0);
  if (T > 1) stageB(1);

  for (int seg = 0; seg < NSEG; seg++) {
#pragma unroll 1
    for (int kk = 0; kk < spt; kk++) {
      const int t = seg * spt + kk;
      const int par = t & 1;
      if (t == T - 1) asm volatile("s_waitcnt vmcnt(0)" ::: "memory");
      else            asm volatile("s_waitcnt vmcnt(2)" ::: "memory");
      __builtin_amdgcn_s_barrier();   // A[t], B[t] landed for ALL waves

      const unsigned short* Ab = As + par * 16384;
      const unsigned short* Bb = Bs + par * 8192;

      // ---- phase a ----
      bf16x8 bfr[4][2], afr[2][2];
#pragma unroll
      for (int fc = 0; fc < 4; fc++)
#pragma unroll
        for (int ks = 0; ks < 2; ks++) {
          const int r = wc * 64 + fc * 16 + lr;
          bfr[fc][ks] = *(const bf16x8*)&Bb[r * 64 + (((ks * 4 + lks) ^ (r & 7)) << 3)];
        }
#pragma unroll
      for (int fr = 0; fr < 2; fr++)
#pragma unroll
        for (int ks = 0; ks < 2; ks++) {
          const int r = wr * 64 + fr * 16 + lr;
          afr[fr][ks] = *(const bf16x8*)&Ab[r * 64 + (((ks * 4 + lks) ^ (r & 7)) << 3)];
        }
      if (t + 1 < T) stageA(par ^ 1);
      asm volatile("s_waitcnt lgkmcnt(0)" ::: "memory");
      __builtin_amdgcn_sched_barrier(0);
      __builtin_amdgcn_s_setprio(1);
#pragma unroll
      for (int fr = 0; fr < 2; fr++)
#pragma unroll
        for (int fc = 0; fc < 4; fc++)
#pragma unroll
          for (int ks = 0; ks < 2; ks++)
            acc[fr][fc] = __builtin_amdgcn_mfma_f32_16x16x32_bf16(
                afr[fr][ks], bfr[fc][ks], acc[fr][fc], 0, 0, 0);
      __builtin_amdgcn_s_setprio(0);
      __builtin_amdgcn_s_barrier();   // B-reads drained before t.b's B-stage

      // ---- phase b ----
#pragma unroll
      for (int fr = 0; fr < 2; fr++)
#pragma unroll
        for (int ks = 0; ks < 2; ks++) {
          const int r = wr * 64 + (fr + 2) * 16 + lr;
          afr[fr][ks] = *(const bf16x8*)&Ab[r * 64 + (((ks * 4 + lks) ^ (r & 7)) << 3)];
        }
      if (t + 2 < T) stageB(par);     // B[t+2] -> Bs[par] (B[t] consumed in ph a)
      asm volatile("s_waitcnt lgkmcnt(0)" ::: "memory");
      __builtin_amdgcn_sched_barrier(0);
      __builtin_amdgcn_s_setprio(1);
#pragma unroll
      for (int fr = 0; fr < 2; fr++)
#pragma unroll
        for (int fc = 0; fc < 4; fc++)
#pragma unroll
          for (int ks = 0; ks < 2; ks++)
            acc[fr + 2][fc] = __builtin_amdgcn_mfma_f32_16x16x32_bf16(
                afr[fr][ks], bfr[fc][ks], acc[fr + 2][fc], 0, 0, 0);
      __builtin_amdgcn_s_setprio(0);
      // no trailing barrier: next-tile vmcnt+barrier provides the sync
    }
    if (EPI == 1) {   // fold this segment's message into acc2 (seg is static)
#pragma unroll
      for (int fr = 0; fr < 4; fr++)
#pragma unroll
        for (int fc = 0; fc < 4; fc++)
#pragma unroll
          for (int rr = 0; rr < 4; rr++) {
            acc2[fr][fc][rr] += pw[seg] * fmaxf(acc[fr][fc][rr] + pb[seg][fc], 0.f);
            acc[fr][fc][rr] = 0.f;
          }
    }
  }

  // ---- epilogue ----
  float bvals[4];
  if (EPI == 2 || EPI == 3) {
#pragma unroll
    for (int fc = 0; fc < 4; fc++) bvals[fc] = bias[col0 + wc * 64 + fc * 16 + lr];
  }
  float* Cf = (float*)Cp;
  unsigned short* Ch = (unsigned short*)Cp;
  const long Coff = (long)zb * sC;

#pragma unroll
  for (int fr = 0; fr < 4; fr++) {
#pragma unroll
    for (int rr = 0; rr < 4; rr++) {
      const int grow = row0 + wr * 64 + fr * 16 + lks * 4 + rr;
#pragma unroll
      for (int fc = 0; fc < 4; fc++) {
        const int gcol = col0 + wc * 64 + fc * 16 + lr;
        const long cidx = Coff + (long)grow * ldc + gcol;
        float v = (EPI == 1) ? acc2[fr][fc][rr] : acc[fr][fc][rr];
        if (EPI == 2) v += bvals[fc] + resid[cidx];
        if (EPI == 3) v = fmaxf(v + bvals[fc], 0.f);
        if (OUT_BF16) Ch[cidx] = f2bf(v);
        else Cf[cidx] = v;
      }
    }
  }
}

// ---------------------------------------------------------------------------
// transpose + fp32->bf16 convert: in[z][R_][C_] f32 -> out[z][C_][R_] bf16
// ---------------------------------------------------------------------------
__global__ __launch_bounds__(256) void transpose_cvt(
    const float* __restrict__ in, unsigned short* __restrict__ out, int R_, int C_) {
  __shared__ float t[32][33];
  const int z = blockIdx.z;
  const float* ib = in + (long)z * R_ * C_;
  unsigned short* ob = out + (long)z * R_ * C_;
  const int r0 = blockIdx.y * 32, c0 = blockIdx.x * 32;
  const int tx = threadIdx.x & 31, ty = threadIdx.x >> 5;
#pragma unroll
  for (int i = 0; i < 4; i++)
    t[ty + i * 8][tx] = ib[(long)(r0 + ty + i * 8) * C_ + c0 + tx];
  __syncthreads();
#pragma unroll
  for (int i = 0; i < 4; i++)
    ob[(long)(c0 + ty + i * 8) * R_ + r0 + tx] = f2bf(t[tx][ty + i * 8]);
}

// ---------------------------------------------------------------------------
// adjn[b,r,n,:] = bf16( adj[b,r,n,:] / max(rowsum,1) )  — one wave per row
// ---------------------------------------------------------------------------
__global__ __launch_bounds__(256) void norm_adj_kernel(const float* __restrict__ adj,
                                                       unsigned short* __restrict__ out,
                                                       long total_rows) {
  const long w = ((long)blockIdx.x * 256 + threadIdx.x) >> 6;
  const int lane = threadIdx.x & 63;
  if (w >= total_rows) return;
  const float* row = adj + w * Ndim;
  float4 f0 = *(const float4*)(row + lane * 8);
  float4 f1 = *(const float4*)(row + lane * 8 + 4);
  float s = f0.x + f0.y + f0.z + f0.w + f1.x + f1.y + f1.z + f1.w;
#pragma unroll
  for (int off = 32; off; off >>= 1) s += __shfl_xor(s, off, 64);
  const float inv = 1.0f / fmaxf(s, 1.0f);
  ushort8 o = {f2bf(f0.x * inv), f2bf(f0.y * inv), f2bf(f0.z * inv), f2bf(f0.w * inv),
               f2bf(f1.x * inv), f2bf(f1.y * inv), f2bf(f1.z * inv), f2bf(f1.w * inv)};
  *(ushort8*)&out[w * Ndim + lane * 8] = o;
}

// ---------------------------------------------------------------------------
// pool partials: part[b][ch][h] = sum_{n in ch*64..+64} x[b,n,h]
// ---------------------------------------------------------------------------
__global__ __launch_bounds__(256) void pool_kernel(const float* __restrict__ x,
                                                   float* __restrict__ part) {
  const int ch = blockIdx.x, b = blockIdx.y, t = threadIdx.x;
  const float* xb = x + ((long)b * Ndim + ch * 64) * Hdim;
  float s0 = 0.f, s1 = 0.f, s2 = 0.f;
  for (int n = 0; n < 64; n++) {
    const float* r = xb + (long)n * Hdim;
    s0 += r[t]; s1 += r[t + 256]; s2 += r[t + 512];
  }
  float* p = part + ((long)b * 8 + ch) * Hdim;
  p[t] = s0; p[t + 256] = s1; p[t + 512] = s2;
}

// ---------------------------------------------------------------------------
// gate: pooled = (sum of partials)/N; logits = pooled@gW + gb; softmax -> w
// ---------------------------------------------------------------------------
__global__ void gate_kernel(const float* __restrict__ part,
                            const float* __restrict__ gW,
                            const float* __restrict__ gb,
                            float* __restrict__ w_out) {
  __shared__ float pooled[Hdim];
  __shared__ float logits[Rdim];
  const int b = blockIdx.x;
  const int h = threadIdx.x;
  float s = 0.f;
#pragma unroll
  for (int c = 0; c < 8; c++) s += part[((long)b * 8 + c) * Hdim + h];
  pooled[h] = s * (1.0f / Ndim);
  __syncthreads();
  if (h < Rdim) {
    float acc = gb[h];
    for (int k = 0; k < Hdim; k++) acc += pooled[k] * gW[k * Rdim + h];
    logits[h] = acc;
  }
  __syncthreads();
  if (h == 0) {
    float mx = -1e30f;
    for (int r = 0; r < Rdim; r++) mx = fmaxf(mx, logits[r]);
    float e[Rdim];
    float se = 0.f;
    for (int r = 0; r < Rdim; r++) { e[r] = expf(logits[r] - mx); se += e[r]; }
    for (int r = 0; r < Rdim; r++) w_out[b * Rdim + r] = e[r] / se;
  }
}

// ---------------------------------------------------------------------------
// out = LayerNorm(X) * g + beta  (single input; residual pre-fused in GEMM)
// ---------------------------------------------------------------------------
__global__ __launch_bounds__(256) void ln_kernel(
    const float* __restrict__ X,
    const float* __restrict__ g, const float* __restrict__ bb,
    float* __restrict__ out, unsigned short* __restrict__ out_bf) {
  __shared__ float red[8];
  const long base = (long)blockIdx.x * Hdim;
  const int t = threadIdx.x;
  float v0 = X[base + t];
  float v1 = X[base + t + 256];
  float v2 = X[base + t + 512];
  float s = v0 + v1 + v2;
  float ss = v0 * v0 + v1 * v1 + v2 * v2;
#pragma unroll
  for (int off = 32; off > 0; off >>= 1) {
    s += __shfl_down(s, off, 64);
    ss += __shfl_down(ss, off, 64);
  }
  const int wid = t >> 6;
  if ((t & 63) == 0) { red[wid] = s; red[4 + wid] = ss; }
  __syncthreads();
  s = red[0] + red[1] + red[2] + red[3];
  ss = red[4] + red[5] + red[6] + red[7];
  const float mu = s * (1.0f / Hdim);
  const float var = ss * (1.0f / Hdim) - mu * mu;
  const float inv = rsqrtf(var + LN_EPS);
  const float o0 = (v0 - mu) * inv * g[t] + bb[t];
  const float o1 = (v1 - mu) * inv * g[t + 256] + bb[t + 256];
  const float o2 = (v2 - mu) * inv * g[t + 512] + bb[t + 512];
  out[base + t] = o0;
  out[base + t + 256] = o1;
  out[base + t + 512] = o2;
  if (out_bf) {
    out_bf[base + t] = f2bf(o0);
    out_bf[base + t + 256] = f2bf(o1);
    out_bf[base + t + 512] = f2bf(o2);
  }
}

// ---------------------------------------------------------------------------
__global__ void stat_kernel(const float* __restrict__ w_buf, float* __restrict__ out) {
  const int r = threadIdx.x;
  if (r < Rdim) {
    float s = 0.f;
    for (int l = 0; l < Ldim; l++)
      for (int b = 0; b < Bdim; b++) s += w_buf[l * Bdim * Rdim + b * Rdim + r];
    out[r] = s * (1.0f / (Ldim * Bdim));
  }
}

extern "C" void kernel_launch(void* const* d_in, const int* in_sizes, int n_in,
                              void* d_out, int out_size, void* d_ws, size_t ws_size,
                              hipStream_t stream) {
  const float* node = (const float*)d_in[0];   // [B,N,H]
  const float* adj  = (const float*)d_in[1];   // [B,R,N,N]
  const float* relW = (const float*)d_in[2];   // [L,R,H,H]
  const float* relb = (const float*)d_in[3];   // [L,R,H]
  const float* gateW = (const float*)d_in[4];  // [L,H,R]
  const float* gateb = (const float*)d_in[5];  // [L,R]
  const float* outW = (const float*)d_in[6];   // [L,H,H]
  const float* outb = (const float*)d_in[7];   // [L,H]
  const float* ln1g = (const float*)d_in[8];
  const float* ln1b = (const float*)d_in[9];
  const float* fW1 = (const float*)d_in[10];   // [L,H,FF]
  const float* fb1 = (const float*)d_in[11];   // [L,FF]
  const float* fW2 = (const float*)d_in[12];   // [L,FF,H]
  const float* fb2 = (const float*)d_in[13];   // [L,H]
  const float* ln2g = (const float*)d_in[14];
  const float* ln2b = (const float*)d_in[15];

  const long BNH = (long)Bdim * Ndim * Hdim;                 // 12,582,912
  const long BRNN = (long)Bdim * Rdim * Ndim * Ndim;         // 41,943,040
  float* xout = (float*)d_out;
  float* stat = xout + BNH;

  // ws layout
  float* ws = (float*)d_ws;
  float* hidden = ws;                          // [B*N,H] f32
  float* tmp    = ws + BNH;                    // [B*N,H] f32; ffh_bf aliases
  unsigned short* agg_all = (unsigned short*)(ws + 2 * BNH);  // [R][B,N,H] bf16
  unsigned short* xT_bf = agg_all + Rdim * BNH;   // [B,H,N] bf16 (hidden_bf alias)
  unsigned short* merged_bf = xT_bf + BNH;        // [B*N,H] bf16
  unsigned short* adjn_bf = merged_bf + BNH;      // [B,R,N,N] bf16
  unsigned short* relWT = adjn_bf + BRNN;         // [L*R,H,H] bf16
  unsigned short* outWT = relWT + (long)Ldim * Rdim * Hdim * Hdim;
  unsigned short* W1T = outWT + (long)Ldim * Hdim * Hdim;
  unsigned short* W2T = W1T + (long)Ldim * Hdim * FFdim;
  float* w_buf = (float*)(W2T + (long)Ldim * FFdim * Hdim);   // [L,B,R]
  float* part = w_buf + Ldim * Bdim * Rdim;                   // [B,8,H]
  unsigned short* hidden_bf = xT_bf;              // alias (xT dead after agg)
  unsigned short* ffh_bf = (unsigned short*)tmp;  // [B*N,FF] bf16 (aliases tmp)
  float* tmp2 = (float*)agg_all;                  // aliases agg_all (dead after msg)

  // ---- one-time prep ----
  {
    const long rows = (long)Bdim * Rdim * Ndim;  // 81920
    norm_adj_kernel<<<(int)(rows / 4), 256, 0, stream>>>(adj, adjn_bf, rows);
  }
  transpose_cvt<<<dim3(Hdim / 32, Hdim / 32, Ldim * Rdim), 256, 0, stream>>>(relW, relWT, Hdim, Hdim);
  transpose_cvt<<<dim3(Hdim / 32, Hdim / 32, Ldim), 256, 0, stream>>>(outW, outWT, Hdim, Hdim);
  transpose_cvt<<<dim3(FFdim / 32, Hdim / 32, Ldim), 256, 0, stream>>>(fW1, W1T, Hdim, FFdim);
  transpose_cvt<<<dim3(Hdim / 32, FFdim / 32, Ldim), 256, 0, stream>>>(fW2, W2T, FFdim, Hdim);

  for (int l = 0; l < Ldim; l++) {
    const float* xin = (l == 0) ? node : xout;

    pool_kernel<<<dim3(8, Bdim), 256, 0, stream>>>(xin, part);
    gate_kernel<<<Bdim, Hdim, 0, stream>>>(
        part, gateW + (long)l * Hdim * Rdim, gateb + (long)l * Rdim,
        w_buf + (long)l * Bdim * Rdim);

    // xT_bf[b][h][n] = x[b][n][h]
    transpose_cvt<<<dim3(Hdim / 32, Ndim / 32, Bdim), 256, 0, stream>>>(xin, xT_bf, Ndim, Hdim);

    // agg_all[r][b] = adjn[b,r] @ x[b]   (all relations, z = r*32+b)
    mfma_gemm<0, true, 1><<<dim3(Hdim / 128, Ndim / 256, Bdim * Rdim), 512, 0, stream>>>(
        adjn_bf, (long)Rdim * Ndim * Ndim, (long)Ndim * Ndim, Ndim,
        xT_bf, (long)Hdim * Ndim, Ndim,
        agg_all, (long)Ndim * Hdim, Hdim,
        Ndim, 0, 0, nullptr, nullptr, nullptr);

    // merged = sum_r w[b,r]*relu(agg_r @ relW[l,r] + relb[l,r])  -> bf16
    mfma_gemm<1, true, Rdim><<<dim3(Hdim / 128, (Bdim * Ndim) / 256, 1), 512, 0, stream>>>(
        agg_all, 0, 0, Hdim,
        relWT + (long)l * Rdim * Hdim * Hdim, 0, Hdim,
        merged_bf, 0, Hdim,
        Hdim, BNH, (long)Hdim * Hdim,
        relb + (long)l * Rdim * Hdim, nullptr,
        w_buf + (long)l * Bdim * Rdim);

    // tmp = merged @ out_W + out_b + xin   (residual fused)
    mfma_gemm<2, false, 1><<<dim3(Hdim / 128, (Bdim * Ndim) / 256, 1), 512, 0, stream>>>(
        merged_bf, 0, 0, Hdim,
        outWT + (long)l * Hdim * Hdim, 0, Hdim,
        tmp, 0, Hdim,
        Hdim, 0, 0,
        outb + (long)l * Hdim, xin, nullptr);

    // hidden = LN(tmp)   (+ bf16 copy for ffn1 A)
    ln_kernel<<<Bdim * Ndim, 256, 0, stream>>>(
        tmp, ln1g + (long)l * Hdim, ln1b + (long)l * Hdim, hidden, hidden_bf);

    // ffh = relu(hidden @ W1 + b1)  -> bf16 (aliases tmp, now dead)
    mfma_gemm<3, true, 1><<<dim3(FFdim / 128, (Bdim * Ndim) / 256, 1), 512, 0, stream>>>(
        hidden_bf, 0, 0, Hdim,
        W1T + (long)l * Hdim * FFdim, 0, Hdim,
        ffh_bf, 0, FFdim,
        Hdim, 0, 0,
        fb1 + (long)l * FFdim, nullptr, nullptr);

    // tmp2 = ffh @ W2 + b2 + hidden  (residual fused; aliases agg_all)
    mfma_gemm<2, false, 1><<<dim3(Hdim / 128, (Bdim * Ndim) / 256, 1), 512, 0, stream>>>(
        ffh_bf, 0, 0, FFdim,
        W2T + (long)l * FFdim * Hdim, 0, FFdim,
        tmp2, 0, Hdim,
        FFdim, 0, 0,
        fb2 + (long)l * Hdim, hidden, nullptr);

    // x = LN(tmp2) -> xout
    ln_kernel<<<Bdim * Ndim, 256, 0, stream>>>(
        tmp2, ln2g + (long)l * Hdim, ln2b + (long)l * Hdim, xout, nullptr);
  }

  stat_kernel<<<1, 64, 0, stream>>>(w_buf, stat);
}